// Round 11
// baseline (445.070 us; speedup 1.0000x reference)
//
#include <hip/hip_runtime.h>
#include <stdint.h>

typedef short v8s __attribute__((ext_vector_type(8)));
typedef float v4f __attribute__((ext_vector_type(4)));
typedef uint16_t u16;

#define NB8   32768            // 262144 / 8 graphs per wave-iter
#define ALPHA 0.2f
#define NEGV  -9000000000000000.0f

__device__ __forceinline__ uint32_t bf16rne(float f) {
    uint32_t u = __float_as_uint(f);
    return (u + 0x7FFFu + ((u >> 16) & 1u)) >> 16;
}
__device__ __forceinline__ uint32_t pk2(float lo, float hi) {
    return bf16rne(lo) | (bf16rne(hi) << 16);
}

// ---- precompute: Wc = W2@W1@W0 (bf16 out), bc = W2@(W1@b0+b1)+b2 — R3 exact ----
__global__ __launch_bounds__(256) void gat_pre(
    const float* __restrict__ W0, const float* __restrict__ b0,
    const float* __restrict__ W1, const float* __restrict__ b1,
    const float* __restrict__ W2, const float* __restrict__ b2,
    float* __restrict__ bc_out, u16* __restrict__ wcb16)
{
    __shared__ float T[64 * 64];
    __shared__ float tb[64];
    const int t = threadIdx.x;
    for (int s = 0; s < 16; ++s) {
        int idx = t + 256 * s; int i = idx >> 6, j = idx & 63;
        float acc = 0.f;
        for (int k = 0; k < 64; ++k) acc = fmaf(W1[i * 64 + k], W0[k * 64 + j], acc);
        T[idx] = acc;
    }
    if (t < 64) {
        float acc = b1[t];
        for (int k = 0; k < 64; ++k) acc = fmaf(W1[t * 64 + k], b0[k], acc);
        tb[t] = acc;
    }
    __syncthreads();
    for (int s = 0; s < 16; ++s) {
        int idx = t + 256 * s; int i = idx >> 6, j = idx & 63;
        float acc = 0.f;
        for (int k = 0; k < 64; ++k) acc = fmaf(W2[i * 64 + k], T[k * 64 + j], acc);
        wcb16[idx] = (u16)bf16rne(acc);
    }
    if (t < 64) {
        float acc = b2[t];
        for (int k = 0; k < 64; ++k) acc = fmaf(W2[t * 64 + k], tb[k], acc);
        bc_out[t] = acc;
    }
}

// ---- main: R10 skeleton; deltas = lane-CONTIGUOUS global reads (via bf16 LDS
//      node-stage, chunk-XOR swizzle) and lane-CONTIGUOUS global stores (via
//      f32 LDS out-stage, per 4-graph half). Math bit-identical to R10. ----
__global__ __launch_bounds__(256, 3) void gat_main(
    const float* __restrict__ node, const int* __restrict__ adj,
    const float* __restrict__ a, const float* __restrict__ bc,
    const u16* __restrict__ wcb16, float* __restrict__ out)
{
    // bufX per wave (6144 B): node bf16 stage, then X tile (aliased — node is
    //   fully in regs before X writes; DS in-order per wave keeps it safe).
    //   layout: row r (0..47) * 128 B; 16-B chunk c stored at c ^ (r&7).
    // bufO per wave (6144 B): out f32 stage for one 4-graph half.
    //   layout: row lr (0..23) * 256 B; 16-B chunk q stored at q ^ ((lr&3)<<2).
    __shared__ __align__(16) u16      bufX[4][3072];
    __shared__ __align__(16) float    bufO[4][1536];
    __shared__ float    ebuf2[4][2][48];
    __shared__ uint32_t pbuf[4][48][4];

    const int tid  = threadIdx.x;
    const int w    = tid >> 6;
    const int lane = tid & 63;
    const int a_   = lane & 15;
    const int h    = lane >> 4;

    uint64_t amask = 0ull;
    #pragma unroll 1
    for (int ij = 0; ij < 36; ++ij) amask |= ((uint64_t)(adj[ij] & 1)) << ij;

    // B fragments: B[k=32kt+8h+e][col=16n+a_] = Wc[16n+a_][k]
    v8s Bw[4][2];
    #pragma unroll
    for (int n = 0; n < 4; ++n)
        #pragma unroll
        for (int kt = 0; kt < 2; ++kt)
            Bw[n][kt] = *(const v8s*)(wcb16 + (16 * n + a_) * 64 + 32 * kt + 8 * h);
    float bcl[4], a_s[4], a_d[4];
    #pragma unroll
    for (int n = 0; n < 4; ++n) {
        bcl[n] = bc[16 * n + a_];
        a_s[n] = a[16 * n + a_];
        a_d[n] = a[64 + 16 * n + a_];
    }

    char*  xs  = (char*)&bufX[w][0];
    char*  osf = (char*)&bufO[w][0];
    float* ebs = &ebuf2[w][0][0];
    float* ebd = &ebuf2[w][1][0];

    const int nwaves = (int)((gridDim.x * blockDim.x) >> 6);
    const int wgid   = (int)((blockIdx.x * blockDim.x + tid) >> 6);

    // preload first tile: CONTIGUOUS — lane i loads 16 B at (m*1024 + 16*i)
    v4f Araw[12];
    {
        const float* nb = node + (size_t)wgid * 3072;
        #pragma unroll
        for (int m = 0; m < 12; ++m)
            Araw[m] = __builtin_nontemporal_load((const v4f*)(nb + m * 256 + 4 * lane));
    }

    #pragma unroll 1
    for (int g = wgid; g < NB8; g += nwaves) {
        // ---- A: stage node tile to LDS as bf16 (swizzled) ----
        #pragma unroll
        for (int m = 0; m < 12; ++m) {
            uint32_t lo = pk2(Araw[m][0], Araw[m][1]);
            uint32_t hi = pk2(Araw[m][2], Araw[m][3]);
            int r    = 4 * m + (lane >> 4);
            int byte = r * 128 + (((((lane & 15) >> 1)) ^ (r & 7)) << 4) + ((lane & 1) << 3);
            uint2 v; v.x = lo; v.y = hi;
            *(uint2*)(xs + byte) = v;                      // ds_write_b64
        }
        // ---- prefetch next tile (contiguous, nt) ----
        if (g + nwaves < NB8) {
            const float* nb = node + (size_t)(g + nwaves) * 3072;
            #pragma unroll
            for (int m = 0; m < 12; ++m)
                Araw[m] = __builtin_nontemporal_load((const v4f*)(nb + m * 256 + 4 * lane));
        }
        // ---- B: read A-fragments (conflict-free swizzled b128) ----
        v8s A[3][2];
        #pragma unroll
        for (int t = 0; t < 3; ++t)
            #pragma unroll
            for (int kt = 0; kt < 2; ++kt) {
                int row = 16 * t + a_;
                A[t][kt] = *(const v8s*)(xs + row * 128 + (((4 * kt + h) ^ (a_ & 7)) << 4));
            }

        // ---- P1: X = node@Wc^T + bc via MFMA -> bf16 X tile; e-partials in regs ----
        #pragma unroll
        for (int t = 0; t < 3; ++t) {
            float es_p[4] = { 0.f, 0.f, 0.f, 0.f };
            float ed_p[4] = { 0.f, 0.f, 0.f, 0.f };
            #pragma unroll
            for (int n = 0; n < 4; ++n) {
                v4f acc = { bcl[n], bcl[n], bcl[n], bcl[n] };
                acc = __builtin_amdgcn_mfma_f32_16x16x32_bf16(A[t][0], Bw[n][0], acc, 0, 0, 0);
                acc = __builtin_amdgcn_mfma_f32_16x16x32_bf16(A[t][1], Bw[n][1], acc, 0, 0, 0);
                uint32_t p01 = pk2(acc[0], acc[1]);
                uint32_t p23 = pk2(acc[2], acc[3]);
                const int colc = 2 * n + (a_ >> 3);        // chunk of col 16n+a_
                const int cin  = (a_ & 7) << 1;            // byte within chunk
                u16 vs0 = (u16)p01, vs1 = (u16)(p01 >> 16);
                u16 vs2 = (u16)p23, vs3 = (u16)(p23 >> 16);
                int row0 = 16 * t + 4 * h;
                *(u16*)(xs + (row0    ) * 128 + ((colc ^ ((row0    ) & 7)) << 4) + cin) = vs0;
                *(u16*)(xs + (row0 + 1) * 128 + ((colc ^ ((row0 + 1) & 7)) << 4) + cin) = vs1;
                *(u16*)(xs + (row0 + 2) * 128 + ((colc ^ ((row0 + 2) & 7)) << 4) + cin) = vs2;
                *(u16*)(xs + (row0 + 3) * 128 + ((colc ^ ((row0 + 3) & 7)) << 4) + cin) = vs3;
                #pragma unroll
                for (int r = 0; r < 4; ++r) {
                    es_p[r] = fmaf(acc[r], a_s[n], es_p[r]);
                    ed_p[r] = fmaf(acc[r], a_d[n], ed_p[r]);
                }
            }
            // reduce over the 16-lane column group (a_ = 0..15)
            #pragma unroll
            for (int r = 0; r < 4; ++r) {
                #pragma unroll
                for (int m = 8; m > 0; m >>= 1) {
                    es_p[r] += __shfl_xor(es_p[r], m, 16);
                    ed_p[r] += __shfl_xor(ed_p[r], m, 16);
                }
            }
            if (a_ == 0) {
                #pragma unroll
                for (int r = 0; r < 4; ++r) ebs[16 * t + 4 * h + r] = es_p[r];
            }
            if (a_ == 1) {
                #pragma unroll
                for (int r = 0; r < 4; ++r) ebd[16 * t + 4 * h + r] = ed_p[r];
            }
        }

        // ---- P3: masked softmax per row (lane = row, 48 active) ----
        if (lane < 48) {
            const int bb = lane / 6;
            const int i6 = lane - 6 * bb;
            float es = ebs[lane];
            float ed[6];
            #pragma unroll
            for (int k = 0; k < 3; ++k)
                *(float2*)&ed[2 * k] = *(const float2*)(ebd + 6 * bb + 2 * k);
            uint32_t rm = (uint32_t)((amask >> (i6 * 6)) & 63u);
            float l[6];
            #pragma unroll
            for (int j = 0; j < 6; ++j) {
                float z  = es + ed[j];
                float lk = fmaxf(z, ALPHA * z);
                l[j] = (rm & (1u << j)) ? lk : NEGV;
            }
            float mm = fmaxf(fmaxf(fmaxf(l[0], l[1]), fmaxf(l[2], l[3])), fmaxf(l[4], l[5]));
            float p[6]; float sum = 0.f;
            #pragma unroll
            for (int j = 0; j < 6; ++j) { p[j] = __expf(l[j] - mm); sum += p[j]; }
            float inv = 1.0f / sum;
            uint4 pk;
            pk.x = pk2(p[0] * inv, p[1] * inv);
            pk.y = pk2(p[2] * inv, p[3] * inv);
            pk.z = pk2(p[4] * inv, p[5] * inv);
            pk.w = 0u;
            *(uint4*)&pbuf[w][lane][0] = pk;
        }

        // ---- P4: out = P@X, per 4-graph half: compute -> LDS stage -> 6
        //      CONTIGUOUS nt dwordx4 stores ----
        float* ob = out + (size_t)g * 3072;
        #pragma unroll
        for (int h2 = 0; h2 < 2; ++h2) {
            const int b2 = lane >> 4;        // graph within half
            const int q  = lane & 15;        // col-quad (cols 4q..4q+3)
            const int B8 = 4 * h2 + b2;      // graph 0..7
            uint2 xd[6];
            #pragma unroll
            for (int j = 0; j < 6; ++j) {
                int rj = 6 * B8 + j;
                xd[j] = *(const uint2*)(xs + rj * 128 + ((((q >> 1)) ^ (rj & 7)) << 4) + ((q & 1) << 3));
            }
            float xr[6][4];
            #pragma unroll
            for (int j = 0; j < 6; ++j) {
                xr[j][0] = __uint_as_float(xd[j].x << 16);
                xr[j][1] = __uint_as_float(xd[j].x & 0xFFFF0000u);
                xr[j][2] = __uint_as_float(xd[j].y << 16);
                xr[j][3] = __uint_as_float(xd[j].y & 0xFFFF0000u);
            }
            #pragma unroll
            for (int i2 = 0; i2 < 6; ++i2) {
                uint4 pu = *(const uint4*)&pbuf[w][6 * B8 + i2][0];
                float p0 = __uint_as_float(pu.x << 16);
                float p1 = __uint_as_float(pu.x & 0xFFFF0000u);
                float p2 = __uint_as_float(pu.y << 16);
                float p3 = __uint_as_float(pu.y & 0xFFFF0000u);
                float p4 = __uint_as_float(pu.z << 16);
                float p5 = __uint_as_float(pu.z & 0xFFFF0000u);
                v4f o;
                #pragma unroll
                for (int c = 0; c < 4; ++c) {
                    float acc0 = p0 * xr[0][c];
                    acc0 = fmaf(p1, xr[1][c], acc0);
                    acc0 = fmaf(p2, xr[2][c], acc0);
                    acc0 = fmaf(p3, xr[3][c], acc0);
                    acc0 = fmaf(p4, xr[4][c], acc0);
                    acc0 = fmaf(p5, xr[5][c], acc0);
                    o[c] = acc0;
                }
                int lr = 6 * b2 + i2;                      // local row 0..23
                int pc = q ^ ((lr & 3) << 2);              // swizzled chunk
                *(v4f*)(osf + lr * 256 + (pc << 4)) = o;   // ds_write_b128
            }
            // contiguous stores: lane i stores 16 B at (m2*1024 + 16*i)
            #pragma unroll
            for (int m2 = 0; m2 < 6; ++m2) {
                int rr  = 4 * m2 + (lane >> 4);
                int pc2 = (lane & 15) ^ ((lane >> 4) << 2);
                v4f v = *(const v4f*)(osf + rr * 256 + (pc2 << 4));
                __builtin_nontemporal_store(v, (v4f*)(ob + h2 * 1536 + m2 * 256 + 4 * lane));
            }
        }
    }
}

extern "C" void kernel_launch(void* const* d_in, const int* in_sizes, int n_in,
                              void* d_out, int out_size, void* d_ws, size_t ws_size,
                              hipStream_t stream)
{
    const float* node = (const float*)d_in[0];
    const int*   adj  = (const int*)d_in[1];
    const float* W0   = (const float*)d_in[2];
    const float* b0   = (const float*)d_in[3];
    const float* W1   = (const float*)d_in[4];
    const float* b1   = (const float*)d_in[5];
    const float* W2   = (const float*)d_in[6];
    const float* b2   = (const float*)d_in[7];
    const float* a    = (const float*)d_in[8];
    float* outp = (float*)d_out;

    float* wsf   = (float*)d_ws;
    float* bcp   = wsf;                      // 64 f32
    u16*   wcb16 = (u16*)(wsf + 64);         // 4096 u16 (16B-aligned)

    gat_pre<<<1, 256, 0, stream>>>(W0, b0, W1, b1, W2, b2, bcp, wcb16);
    gat_main<<<1024, 256, 0, stream>>>(node, adj, a, bcp, wcb16, outp);
}

// Round 12
// 200.907 us; speedup vs baseline: 2.2153x; 2.2153x over previous
//
#include <hip/hip_runtime.h>
#include <stdint.h>

typedef short v8s __attribute__((ext_vector_type(8)));
typedef float v4f __attribute__((ext_vector_type(4)));
typedef uint16_t u16;

#define NB8   32768            // 262144 / 8 graphs per wave-iter
#define ALPHA 0.2f
#define NEGV  -9000000000000000.0f

__device__ __forceinline__ uint32_t bf16rne(float f) {
    uint32_t u = __float_as_uint(f);
    return (u + 0x7FFFu + ((u >> 16) & 1u)) >> 16;
}
__device__ __forceinline__ uint32_t pk2(float lo, float hi) {
    return bf16rne(lo) | (bf16rne(hi) << 16);
}

// ---- precompute: Wc = W2@W1@W0 (bf16 out), bc = W2@(W1@b0+b1)+b2 — R3 exact ----
__global__ __launch_bounds__(256) void gat_pre(
    const float* __restrict__ W0, const float* __restrict__ b0,
    const float* __restrict__ W1, const float* __restrict__ b1,
    const float* __restrict__ W2, const float* __restrict__ b2,
    float* __restrict__ bc_out, u16* __restrict__ wcb16)
{
    __shared__ float T[64 * 64];
    __shared__ float tb[64];
    const int t = threadIdx.x;
    for (int s = 0; s < 16; ++s) {
        int idx = t + 256 * s; int i = idx >> 6, j = idx & 63;
        float acc = 0.f;
        for (int k = 0; k < 64; ++k) acc = fmaf(W1[i * 64 + k], W0[k * 64 + j], acc);
        T[idx] = acc;
    }
    if (t < 64) {
        float acc = b1[t];
        for (int k = 0; k < 64; ++k) acc = fmaf(W1[t * 64 + k], b0[k], acc);
        tb[t] = acc;
    }
    __syncthreads();
    for (int s = 0; s < 16; ++s) {
        int idx = t + 256 * s; int i = idx >> 6, j = idx & 63;
        float acc = 0.f;
        for (int k = 0; k < 64; ++k) acc = fmaf(W2[i * 64 + k], T[k * 64 + j], acc);
        wcb16[idx] = (u16)bf16rne(acc);
    }
    if (t < 64) {
        float acc = b2[t];
        for (int k = 0; k < 64; ++k) acc = fmaf(W2[t * 64 + k], tb[k], acc);
        bc_out[t] = acc;
    }
}

// ---- main: R10 kernel; deltas = {prefetch split into two 6-KB halves at two
//      program points, grid 1280 (20 waves/CU)} — request-injection smoothing ----
__global__ __launch_bounds__(256, 2) void gat_main(
    const float* __restrict__ node, const int* __restrict__ adj,
    const float* __restrict__ a, const float* __restrict__ bc,
    const u16* __restrict__ wcb16, float* __restrict__ out)
{
    // X tile bf16: row j (0..47), physical col = c ^ (16*((j>>2)&3))
    __shared__ u16      xtile[4][48 * 64];  // 24576 B
    __shared__ float    ebuf2[4][2][48];    // 1536 B: [0]=e_src, [1]=e_dst per row
    __shared__ uint32_t pbuf[4][48][4];     // 3072 B: softmax rows packed bf16

    const int tid  = threadIdx.x;
    const int w    = tid >> 6;
    const int lane = tid & 63;
    const int a_   = lane & 15;
    const int h    = lane >> 4;

    uint64_t amask = 0ull;
    #pragma unroll 1
    for (int ij = 0; ij < 36; ++ij) amask |= ((uint64_t)(adj[ij] & 1)) << ij;

    // B fragments: B[k=32kt+8h+e][col=16n+a_] = Wc[16n+a_][k]
    v8s Bw[4][2];
    #pragma unroll
    for (int n = 0; n < 4; ++n)
        #pragma unroll
        for (int kt = 0; kt < 2; ++kt)
            Bw[n][kt] = *(const v8s*)(wcb16 + (16 * n + a_) * 64 + 32 * kt + 8 * h);
    float bcl[4], a_s[4], a_d[4];
    #pragma unroll
    for (int n = 0; n < 4; ++n) {
        bcl[n] = bc[16 * n + a_];
        a_s[n] = a[16 * n + a_];
        a_d[n] = a[64 + 16 * n + a_];
    }

    u16*   xt  = &xtile[w][0];
    float* ebs = &ebuf2[w][0][0];
    float* ebd = &ebuf2[w][1][0];

    const int nwaves = (int)((gridDim.x * blockDim.x) >> 6);
    const int wgid   = (int)((blockIdx.x * blockDim.x + tid) >> 6);

    // preload first tile: lane holds node[row=16t+a_][k=32kt+8h .. +8] (f32)
    v4f Araw[3][2][2];
    {
        const char* nb = (const char*)node + (size_t)wgid * 12288 + a_ * 256 + h * 32;
        #pragma unroll
        for (int t = 0; t < 3; ++t) {
            const char* bt = nb + t * 4096;
            Araw[t][0][0] = __builtin_nontemporal_load((const v4f*)(bt));
            Araw[t][0][1] = __builtin_nontemporal_load((const v4f*)(bt + 16));
            Araw[t][1][0] = __builtin_nontemporal_load((const v4f*)(bt + 128));
            Araw[t][1][1] = __builtin_nontemporal_load((const v4f*)(bt + 144));
        }
    }

    #pragma unroll 1
    for (int g = wgid; g < NB8; g += nwaves) {
        // ---- pack A fragments (bf16, pure C rne) ----
        v8s A[3][2];
        #pragma unroll
        for (int t = 0; t < 3; ++t)
            #pragma unroll
            for (int kt = 0; kt < 2; ++kt) {
                union { uint32_t u[4]; v8s v; } f;
                f.u[0] = pk2(Araw[t][kt][0][0], Araw[t][kt][0][1]);
                f.u[1] = pk2(Araw[t][kt][0][2], Araw[t][kt][0][3]);
                f.u[2] = pk2(Araw[t][kt][1][0], Araw[t][kt][1][1]);
                f.u[3] = pk2(Araw[t][kt][1][2], Araw[t][kt][1][3]);
                A[t][kt] = f.v;
            }
        // ---- prefetch half 1 (t = 0,1 of next tile) ----
        const bool more = (g + nwaves < NB8);
        if (more) {
            const char* nb = (const char*)node + (size_t)(g + nwaves) * 12288 + a_ * 256 + h * 32;
            #pragma unroll
            for (int t = 0; t < 2; ++t) {
                const char* bt = nb + t * 4096;
                Araw[t][0][0] = __builtin_nontemporal_load((const v4f*)(bt));
                Araw[t][0][1] = __builtin_nontemporal_load((const v4f*)(bt + 16));
                Araw[t][1][0] = __builtin_nontemporal_load((const v4f*)(bt + 128));
                Araw[t][1][1] = __builtin_nontemporal_load((const v4f*)(bt + 144));
            }
        }

        // ---- P1: X = node@Wc^T + bc via MFMA -> bf16 tile; e-partials in regs ----
        #pragma unroll
        for (int t = 0; t < 3; ++t) {
            float es_p[4] = { 0.f, 0.f, 0.f, 0.f };
            float ed_p[4] = { 0.f, 0.f, 0.f, 0.f };
            #pragma unroll
            for (int n = 0; n < 4; ++n) {
                v4f acc = { bcl[n], bcl[n], bcl[n], bcl[n] };
                acc = __builtin_amdgcn_mfma_f32_16x16x32_bf16(A[t][0], Bw[n][0], acc, 0, 0, 0);
                acc = __builtin_amdgcn_mfma_f32_16x16x32_bf16(A[t][1], Bw[n][1], acc, 0, 0, 0);
                uint32_t p01 = pk2(acc[0], acc[1]);
                uint32_t p23 = pk2(acc[2], acc[3]);
                const int cb = (16 * n + a_) ^ (h << 4);      // swizzled physical col
                const int rb = (16 * t + 4 * h) * 64 + cb;    // rows 16t+4h+r
                xt[rb]       = (u16)p01;
                xt[rb + 64]  = (u16)(p01 >> 16);
                xt[rb + 128] = (u16)p23;
                xt[rb + 192] = (u16)(p23 >> 16);
                #pragma unroll
                for (int r = 0; r < 4; ++r) {
                    es_p[r] = fmaf(acc[r], a_s[n], es_p[r]);
                    ed_p[r] = fmaf(acc[r], a_d[n], ed_p[r]);
                }
            }
            // reduce over the 16-lane column group (a_ = 0..15)
            #pragma unroll
            for (int r = 0; r < 4; ++r) {
                #pragma unroll
                for (int m = 8; m > 0; m >>= 1) {
                    es_p[r] += __shfl_xor(es_p[r], m, 16);
                    ed_p[r] += __shfl_xor(ed_p[r], m, 16);
                }
            }
            if (a_ == 0) {
                #pragma unroll
                for (int r = 0; r < 4; ++r) ebs[16 * t + 4 * h + r] = es_p[r];
            }
            if (a_ == 1) {
                #pragma unroll
                for (int r = 0; r < 4; ++r) ebd[16 * t + 4 * h + r] = ed_p[r];
            }
        }

        // ---- P3: masked softmax per row (lane = row, 48 active) ----
        if (lane < 48) {
            const int bb = lane / 6;
            const int i6 = lane - 6 * bb;
            float es = ebs[lane];
            float ed[6];
            #pragma unroll
            for (int k = 0; k < 3; ++k)
                *(float2*)&ed[2 * k] = *(const float2*)(ebd + 6 * bb + 2 * k);
            uint32_t rm = (uint32_t)((amask >> (i6 * 6)) & 63u);
            float l[6];
            #pragma unroll
            for (int j = 0; j < 6; ++j) {
                float z  = es + ed[j];
                float lk = fmaxf(z, ALPHA * z);
                l[j] = (rm & (1u << j)) ? lk : NEGV;
            }
            float mm = fmaxf(fmaxf(fmaxf(l[0], l[1]), fmaxf(l[2], l[3])), fmaxf(l[4], l[5]));
            float p[6]; float sum = 0.f;
            #pragma unroll
            for (int j = 0; j < 6; ++j) { p[j] = __expf(l[j] - mm); sum += p[j]; }
            float inv = 1.0f / sum;
            uint4 pk;
            pk.x = pk2(p[0] * inv, p[1] * inv);
            pk.y = pk2(p[2] * inv, p[3] * inv);
            pk.z = pk2(p[4] * inv, p[5] * inv);
            pk.w = 0u;
            *(uint4*)&pbuf[w][lane][0] = pk;
        }

        // ---- prefetch half 2 (t = 2 of next tile) — issued here so it flies
        //      under P4's stores and the next iter's A-pack ----
        if (more) {
            const char* nb = (const char*)node + (size_t)(g + nwaves) * 12288 + a_ * 256 + h * 32;
            const char* bt = nb + 2 * 4096;
            Araw[2][0][0] = __builtin_nontemporal_load((const v4f*)(bt));
            Araw[2][0][1] = __builtin_nontemporal_load((const v4f*)(bt + 16));
            Araw[2][1][0] = __builtin_nontemporal_load((const v4f*)(bt + 128));
            Araw[2][1][1] = __builtin_nontemporal_load((const v4f*)(bt + 144));
        }
        __builtin_amdgcn_sched_barrier(0);   // keep half-2 loads above P4 stores

        // ---- P4: out = P@X; lane (b=lane>>3, q=lane&7) owns cols 8q..8q+7 of
        //      graph b. 6 b128 X reads + 6 broadcast b128 p reads + 12 nt
        //      v4f stores. ----
        {
            const int b = lane >> 3;
            const int q = lane & 7;
            union { uint4 v; u16 s[8]; } xu[6];
            #pragma unroll
            for (int j = 0; j < 6; ++j) {
                int rj = 6 * b + j;
                int cp = (8 * q) ^ ((((rj >> 2) & 3)) << 4);   // physical col (8-contig)
                xu[j].v = *(const uint4*)(xt + rj * 64 + cp);
            }
            float* dst = out + ((size_t)(g * 8 + b)) * 384 + 8 * q;
            #pragma unroll
            for (int i2 = 0; i2 < 6; ++i2) {
                uint4 pu = *(const uint4*)&pbuf[w][6 * b + i2][0];
                float p[6];
                p[0] = __uint_as_float(pu.x << 16);
                p[1] = __uint_as_float(pu.x & 0xFFFF0000u);
                p[2] = __uint_as_float(pu.y << 16);
                p[3] = __uint_as_float(pu.y & 0xFFFF0000u);
                p[4] = __uint_as_float(pu.z << 16);
                p[5] = __uint_as_float(pu.z & 0xFFFF0000u);
                float o[8];
                #pragma unroll
                for (int c = 0; c < 8; ++c) {
                    float acc0 = p[0] * __uint_as_float(((uint32_t)xu[0].s[c]) << 16);
                    acc0 = fmaf(p[1], __uint_as_float(((uint32_t)xu[1].s[c]) << 16), acc0);
                    acc0 = fmaf(p[2], __uint_as_float(((uint32_t)xu[2].s[c]) << 16), acc0);
                    acc0 = fmaf(p[3], __uint_as_float(((uint32_t)xu[3].s[c]) << 16), acc0);
                    acc0 = fmaf(p[4], __uint_as_float(((uint32_t)xu[4].s[c]) << 16), acc0);
                    acc0 = fmaf(p[5], __uint_as_float(((uint32_t)xu[5].s[c]) << 16), acc0);
                    o[c] = acc0;
                }
                v4f o0 = { o[0], o[1], o[2], o[3] };
                v4f o1 = { o[4], o[5], o[6], o[7] };
                __builtin_nontemporal_store(o0, (v4f*)(dst + i2 * 64));
                __builtin_nontemporal_store(o1, (v4f*)(dst + i2 * 64 + 4));
            }
        }
    }
}

extern "C" void kernel_launch(void* const* d_in, const int* in_sizes, int n_in,
                              void* d_out, int out_size, void* d_ws, size_t ws_size,
                              hipStream_t stream)
{
    const float* node = (const float*)d_in[0];
    const int*   adj  = (const int*)d_in[1];
    const float* W0   = (const float*)d_in[2];
    const float* b0   = (const float*)d_in[3];
    const float* W1   = (const float*)d_in[4];
    const float* b1   = (const float*)d_in[5];
    const float* W2   = (const float*)d_in[6];
    const float* b2   = (const float*)d_in[7];
    const float* a    = (const float*)d_in[8];
    float* outp = (float*)d_out;

    float* wsf   = (float*)d_ws;
    float* bcp   = wsf;                      // 64 f32
    u16*   wcb16 = (u16*)(wsf + 64);         // 4096 u16 (16B-aligned)

    gat_pre<<<1, 256, 0, stream>>>(W0, b0, W1, b1, W2, b2, bcp, wcb16);
    gat_main<<<1280, 256, 0, stream>>>(node, adj, a, bcp, wcb16, outp);
}

// Round 13
// 198.303 us; speedup vs baseline: 2.2444x; 1.0131x over previous
//
#include <hip/hip_runtime.h>
#include <stdint.h>

typedef short v8s __attribute__((ext_vector_type(8)));
typedef float v4f __attribute__((ext_vector_type(4)));
typedef uint16_t u16;

#define NB8   32768            // 262144 / 8 graphs per wave-iter
#define ALPHA 0.2f
#define NEGV  -9000000000000000.0f

__device__ __forceinline__ uint32_t bf16rne(float f) {
    uint32_t u = __float_as_uint(f);
    return (u + 0x7FFFu + ((u >> 16) & 1u)) >> 16;
}
__device__ __forceinline__ uint32_t pk2(float lo, float hi) {
    return bf16rne(lo) | (bf16rne(hi) << 16);
}

// ---- precompute: Wc = W2@W1@W0 (bf16 out), bc = W2@(W1@b0+b1)+b2 — R3 exact ----
__global__ __launch_bounds__(256) void gat_pre(
    const float* __restrict__ W0, const float* __restrict__ b0,
    const float* __restrict__ W1, const float* __restrict__ b1,
    const float* __restrict__ W2, const float* __restrict__ b2,
    float* __restrict__ bc_out, u16* __restrict__ wcb16)
{
    __shared__ float T[64 * 64];
    __shared__ float tb[64];
    const int t = threadIdx.x;
    for (int s = 0; s < 16; ++s) {
        int idx = t + 256 * s; int i = idx >> 6, j = idx & 63;
        float acc = 0.f;
        for (int k = 0; k < 64; ++k) acc = fmaf(W1[i * 64 + k], W0[k * 64 + j], acc);
        T[idx] = acc;
    }
    if (t < 64) {
        float acc = b1[t];
        for (int k = 0; k < 64; ++k) acc = fmaf(W1[t * 64 + k], b0[k], acc);
        tb[t] = acc;
    }
    __syncthreads();
    for (int s = 0; s < 16; ++s) {
        int idx = t + 256 * s; int i = idx >> 6, j = idx & 63;
        float acc = 0.f;
        for (int k = 0; k < 64; ++k) acc = fmaf(W2[i * 64 + k], T[k * 64 + j], acc);
        wcb16[idx] = (u16)bf16rne(acc);
    }
    if (t < 64) {
        float acc = b2[t];
        for (int k = 0; k < 64; ++k) acc = fmaf(W2[t * 64 + k], tb[k], acc);
        bc_out[t] = acc;
    }
}

// ---- main: R12 kernel; ONLY delta = contiguous global reads bounced through
//      the (aliased) xtile buffer: 12 nt v4f contiguous loads -> pk2 ->
//      12 ds_write_b64 (node-stage layout, 2-way free) -> 6 ds_read_b128
//      A-frags (R7-proven conflict-free). P1/P3/P4 byte-identical to R12. ----
__global__ __launch_bounds__(256, 2) void gat_main(
    const float* __restrict__ node, const int* __restrict__ adj,
    const float* __restrict__ a, const float* __restrict__ bc,
    const u16* __restrict__ wcb16, float* __restrict__ out)
{
    // xtile dual-use per iter phase:
    //  (1) node-stage bf16: row r (0..47) stride 128 B; 16-B chunk c at c^(r&7)
    //  (2) X tile bf16:     row j stride 128 B; u16 col c' at c'^(16*((j>>2)&3))
    __shared__ u16      xtile[4][48 * 64];  // 24576 B
    __shared__ float    ebuf2[4][2][48];    // 1536 B
    __shared__ uint32_t pbuf[4][48][4];     // 3072 B

    const int tid  = threadIdx.x;
    const int w    = tid >> 6;
    const int lane = tid & 63;
    const int a_   = lane & 15;
    const int h    = lane >> 4;

    uint64_t amask = 0ull;
    #pragma unroll 1
    for (int ij = 0; ij < 36; ++ij) amask |= ((uint64_t)(adj[ij] & 1)) << ij;

    // B fragments: B[k=32kt+8h+e][col=16n+a_] = Wc[16n+a_][k]
    v8s Bw[4][2];
    #pragma unroll
    for (int n = 0; n < 4; ++n)
        #pragma unroll
        for (int kt = 0; kt < 2; ++kt)
            Bw[n][kt] = *(const v8s*)(wcb16 + (16 * n + a_) * 64 + 32 * kt + 8 * h);
    float bcl[4], a_s[4], a_d[4];
    #pragma unroll
    for (int n = 0; n < 4; ++n) {
        bcl[n] = bc[16 * n + a_];
        a_s[n] = a[16 * n + a_];
        a_d[n] = a[64 + 16 * n + a_];
    }

    u16*   xt  = &xtile[w][0];
    char*  xc  = (char*)xt;
    float* ebs = &ebuf2[w][0][0];
    float* ebd = &ebuf2[w][1][0];

    const int nwaves = (int)((gridDim.x * blockDim.x) >> 6);
    const int wgid   = (int)((blockIdx.x * blockDim.x + tid) >> 6);

    // node-stage write address (per chunk m): row r = 4m + h2, chunk (l&15)>>1
    const int h2   = lane >> 4;              // = h
    const int wc_  = (lane & 15) >> 1;       // chunk id
    const int wofs = (lane & 1) << 3;        // 8-B half

    // preload first tile: CONTIGUOUS — lane l loads 16 B at (m*1024 + 16*l)
    v4f Araw[12];
    {
        const float* nb = node + (size_t)wgid * 3072;
        #pragma unroll
        for (int m = 0; m < 12; ++m)
            Araw[m] = __builtin_nontemporal_load((const v4f*)(nb + m * 256 + 4 * lane));
    }

    #pragma unroll 1
    for (int g = wgid; g < NB8; g += nwaves) {
        // ---- stage node tile to LDS (pack bf16 lane-local, b64 writes) ----
        #pragma unroll
        for (int m = 0; m < 12; ++m) {
            uint2 v;
            v.x = pk2(Araw[m][0], Araw[m][1]);
            v.y = pk2(Araw[m][2], Araw[m][3]);
            int r = 4 * m + h2;
            *(uint2*)(xc + r * 128 + ((wc_ ^ (r & 7)) << 4) + wofs) = v;
        }
        // ---- prefetch next tile (contiguous, nt; skip last iter) ----
        if (g + nwaves < NB8) {
            const float* nb = node + (size_t)(g + nwaves) * 3072;
            #pragma unroll
            for (int m = 0; m < 12; ++m)
                Araw[m] = __builtin_nontemporal_load((const v4f*)(nb + m * 256 + 4 * lane));
        }
        // ---- A-frags from LDS (conflict-free b128) ----
        v8s A[3][2];
        #pragma unroll
        for (int t = 0; t < 3; ++t)
            #pragma unroll
            for (int kt = 0; kt < 2; ++kt)
                A[t][kt] = *(const v8s*)(xc + (16 * t + a_) * 128 + (((4 * kt + h) ^ (a_ & 7)) << 4));

        // ---- P1: X = node@Wc^T + bc via MFMA -> bf16 tile; e-partials in regs ----
        #pragma unroll
        for (int t = 0; t < 3; ++t) {
            float es_p[4] = { 0.f, 0.f, 0.f, 0.f };
            float ed_p[4] = { 0.f, 0.f, 0.f, 0.f };
            #pragma unroll
            for (int n = 0; n < 4; ++n) {
                v4f acc = { bcl[n], bcl[n], bcl[n], bcl[n] };
                acc = __builtin_amdgcn_mfma_f32_16x16x32_bf16(A[t][0], Bw[n][0], acc, 0, 0, 0);
                acc = __builtin_amdgcn_mfma_f32_16x16x32_bf16(A[t][1], Bw[n][1], acc, 0, 0, 0);
                uint32_t p01 = pk2(acc[0], acc[1]);
                uint32_t p23 = pk2(acc[2], acc[3]);
                const int cb = (16 * n + a_) ^ (h << 4);      // swizzled physical col
                const int rb = (16 * t + 4 * h) * 64 + cb;    // rows 16t+4h+r
                xt[rb]       = (u16)p01;
                xt[rb + 64]  = (u16)(p01 >> 16);
                xt[rb + 128] = (u16)p23;
                xt[rb + 192] = (u16)(p23 >> 16);
                #pragma unroll
                for (int r = 0; r < 4; ++r) {
                    es_p[r] = fmaf(acc[r], a_s[n], es_p[r]);
                    ed_p[r] = fmaf(acc[r], a_d[n], ed_p[r]);
                }
            }
            // reduce over the 16-lane column group (a_ = 0..15)
            #pragma unroll
            for (int r = 0; r < 4; ++r) {
                #pragma unroll
                for (int m = 8; m > 0; m >>= 1) {
                    es_p[r] += __shfl_xor(es_p[r], m, 16);
                    ed_p[r] += __shfl_xor(ed_p[r], m, 16);
                }
            }
            if (a_ == 0) {
                #pragma unroll
                for (int r = 0; r < 4; ++r) ebs[16 * t + 4 * h + r] = es_p[r];
            }
            if (a_ == 1) {
                #pragma unroll
                for (int r = 0; r < 4; ++r) ebd[16 * t + 4 * h + r] = ed_p[r];
            }
        }

        // ---- P3: masked softmax per row (lane = row, 48 active) ----
        if (lane < 48) {
            const int bb = lane / 6;
            const int i6 = lane - 6 * bb;
            float es = ebs[lane];
            float ed[6];
            #pragma unroll
            for (int k = 0; k < 3; ++k)
                *(float2*)&ed[2 * k] = *(const float2*)(ebd + 6 * bb + 2 * k);
            uint32_t rm = (uint32_t)((amask >> (i6 * 6)) & 63u);
            float l[6];
            #pragma unroll
            for (int j = 0; j < 6; ++j) {
                float z  = es + ed[j];
                float lk = fmaxf(z, ALPHA * z);
                l[j] = (rm & (1u << j)) ? lk : NEGV;
            }
            float mm = fmaxf(fmaxf(fmaxf(l[0], l[1]), fmaxf(l[2], l[3])), fmaxf(l[4], l[5]));
            float p[6]; float sum = 0.f;
            #pragma unroll
            for (int j = 0; j < 6; ++j) { p[j] = __expf(l[j] - mm); sum += p[j]; }
            float inv = 1.0f / sum;
            uint4 pk;
            pk.x = pk2(p[0] * inv, p[1] * inv);
            pk.y = pk2(p[2] * inv, p[3] * inv);
            pk.z = pk2(p[4] * inv, p[5] * inv);
            pk.w = 0u;
            *(uint4*)&pbuf[w][lane][0] = pk;
        }

        // ---- P4: out = P@X; lane (b=lane>>3, q=lane&7) owns cols 8q..8q+7 of
        //      graph b. 6 b128 X reads + 6 broadcast b128 p reads + 12 nt
        //      v4f stores. ----
        {
            const int b = lane >> 3;
            const int q = lane & 7;
            union { uint4 v; u16 s[8]; } xu[6];
            #pragma unroll
            for (int j = 0; j < 6; ++j) {
                int rj = 6 * b + j;
                int cp = (8 * q) ^ ((((rj >> 2) & 3)) << 4);   // physical col (8-contig)
                xu[j].v = *(const uint4*)(xt + rj * 64 + cp);
            }
            float* dst = out + ((size_t)(g * 8 + b)) * 384 + 8 * q;
            #pragma unroll
            for (int i2 = 0; i2 < 6; ++i2) {
                uint4 pu = *(const uint4*)&pbuf[w][6 * b + i2][0];
                float p[6];
                p[0] = __uint_as_float(pu.x << 16);
                p[1] = __uint_as_float(pu.x & 0xFFFF0000u);
                p[2] = __uint_as_float(pu.y << 16);
                p[3] = __uint_as_float(pu.y & 0xFFFF0000u);
                p[4] = __uint_as_float(pu.z << 16);
                p[5] = __uint_as_float(pu.z & 0xFFFF0000u);
                float o[8];
                #pragma unroll
                for (int c = 0; c < 8; ++c) {
                    float acc0 = p[0] * __uint_as_float(((uint32_t)xu[0].s[c]) << 16);
                    acc0 = fmaf(p[1], __uint_as_float(((uint32_t)xu[1].s[c]) << 16), acc0);
                    acc0 = fmaf(p[2], __uint_as_float(((uint32_t)xu[2].s[c]) << 16), acc0);
                    acc0 = fmaf(p[3], __uint_as_float(((uint32_t)xu[3].s[c]) << 16), acc0);
                    acc0 = fmaf(p[4], __uint_as_float(((uint32_t)xu[4].s[c]) << 16), acc0);
                    acc0 = fmaf(p[5], __uint_as_float(((uint32_t)xu[5].s[c]) << 16), acc0);
                    o[c] = acc0;
                }
                v4f o0 = { o[0], o[1], o[2], o[3] };
                v4f o1 = { o[4], o[5], o[6], o[7] };
                __builtin_nontemporal_store(o0, (v4f*)(dst + i2 * 64));
                __builtin_nontemporal_store(o1, (v4f*)(dst + i2 * 64 + 4));
            }
        }
    }
}

extern "C" void kernel_launch(void* const* d_in, const int* in_sizes, int n_in,
                              void* d_out, int out_size, void* d_ws, size_t ws_size,
                              hipStream_t stream)
{
    const float* node = (const float*)d_in[0];
    const int*   adj  = (const int*)d_in[1];
    const float* W0   = (const float*)d_in[2];
    const float* b0   = (const float*)d_in[3];
    const float* W1   = (const float*)d_in[4];
    const float* b1   = (const float*)d_in[5];
    const float* W2   = (const float*)d_in[6];
    const float* b2   = (const float*)d_in[7];
    const float* a    = (const float*)d_in[8];
    float* outp = (float*)d_out;

    float* wsf   = (float*)d_ws;
    float* bcp   = wsf;                      // 64 f32
    u16*   wcb16 = (u16*)(wsf + 64);         // 4096 u16 (16B-aligned)

    gat_pre<<<1, 256, 0, stream>>>(W0, b0, W1, b1, W2, b2, bcp, wcb16);
    gat_main<<<1280, 256, 0, stream>>>(node, adj, a, bcp, wcb16, outp);
}